// Round 10
// baseline (117.067 us; speedup 1.0000x reference)
//
#include <hip/hip_runtime.h>

// ShiftedPatchTokenization on MI355X (gfx950)
// x[64,3,224,224] f32 -> out[64,196,768] f32
// fold_w (+G/Bt partials) -> gb reduce -> pack (512thr vec4, XCD-swizzled) ->
// 224x96 GEMM: A via dbuf LDS, B direct L2->register (prefetched 1 K-step).

typedef short bf16x8 __attribute__((ext_vector_type(8)));
typedef unsigned short u16x8 __attribute__((ext_vector_type(8)));
typedef float f32x4 __attribute__((ext_vector_type(4)));

#define GLOBAL_AS __attribute__((address_space(1)))
#define LDS_AS __attribute__((address_space(3)))

__device__ __forceinline__ unsigned short f2bf(float f) {
  union { float f; unsigned int u; } v;
  v.f = f;
  unsigned int u = v.u;
  unsigned int r = (u + 0x7FFFu + ((u >> 16) & 1u)) >> 16;  // RNE
  return (unsigned short)r;
}

// ---------------------------------------------------------------------------
// Kernel 1: fold gamma*w over duplicated shift groups -> w2t[768][2304] bf16,
// plus per-f2-block partial sums. grid (144, 3), block 256
// ---------------------------------------------------------------------------
__global__ __launch_bounds__(256) void spt_fold_w(
    const float* __restrict__ gamma, const float* __restrict__ beta,
    const float* __restrict__ w, unsigned short* __restrict__ w2t,
    float* __restrict__ Gp, float* __restrict__ Bp)
{
  __shared__ float tile[16][257];
  const int f2blk = blockIdx.x * 16;
  const int jblk  = blockIdx.y * 256;
  const int t = threadIdx.x;
  const int j = jblk + t;
  float gacc = 0.f, bacc = 0.f;
  #pragma unroll
  for (int i = 0; i < 16; ++i) {
    const int f2 = f2blk + i;
    const int g = f2 / 768;
    const int rem = f2 % 768;  // c*256 + p1*16 + p2
    float v, bv;
    if (g == 0) {
      const int f = rem;
      const float wv = w[(size_t)f * 768 + j];
      v = gamma[f] * wv;
      bv = beta[f] * wv;
    } else if (g == 1) {
      const int fa = 768 + rem, fb = 2304 + rem;   // left_up, left_down
      const float wa = w[(size_t)fa * 768 + j], wb = w[(size_t)fb * 768 + j];
      v = gamma[fa] * wa + gamma[fb] * wb;
      bv = beta[fa] * wa + beta[fb] * wb;
    } else {
      const int fa = 1536 + rem, fb = 3072 + rem;  // right_up, right_down
      const float wa = w[(size_t)fa * 768 + j], wb = w[(size_t)fb * 768 + j];
      v = gamma[fa] * wa + gamma[fb] * wb;
      bv = beta[fa] * wa + beta[fb] * wb;
    }
    tile[i][t] = v;
    gacc += v;
    bacc += bv;
  }
  __syncthreads();
  u16x8 lo, hi;
  #pragma unroll
  for (int i = 0; i < 8; ++i) {
    lo[i] = f2bf(tile[i][t]);
    hi[i] = f2bf(tile[8 + i][t]);
  }
  unsigned short* dst = w2t + (size_t)j * 2304 + f2blk;
  *(u16x8*)dst = lo;
  *(u16x8*)(dst + 8) = hi;
  Gp[blockIdx.x * 768 + j] = gacc;
  Bp[blockIdx.x * 768 + j] = bacc;
}

// ---------------------------------------------------------------------------
// Kernel 2: reduce 144 partials -> G[768], Bt[768] (+b). grid 3, block 256
// ---------------------------------------------------------------------------
__global__ __launch_bounds__(256) void spt_gb(
    const float* __restrict__ Gp, const float* __restrict__ Bp,
    const float* __restrict__ bvec, float* __restrict__ G, float* __restrict__ Bt)
{
  const int j = blockIdx.x * 256 + threadIdx.x;
  float g = 0.f, bb = 0.f;
  for (int i = 0; i < 144; ++i) {
    g += Gp[i * 768 + j];
    bb += Bp[i * 768 + j];
  }
  G[j] = g;
  Bt[j] = bb + bvec[j];
}

// ---------------------------------------------------------------------------
// Kernel 3: pack V[12544][2304] bf16 + per-token LN stats (r, -mu*r)
// 512 threads: 8 groups x 56 x-quads, 6 serial (c,p1) iters.
// XCD chunk swizzle (896 = 8*112 exact): (b,hi) neighbors share an XCD so the
// y+-1 interp rows L2-hit. grid 896.
// ---------------------------------------------------------------------------
__global__ __launch_bounds__(512) void spt_pack(
    const float* __restrict__ x, unsigned short* __restrict__ V,
    float2* __restrict__ stats)
{
  __shared__ unsigned short slab[14 * 2312];  // token-major, +8 pad per row
  __shared__ float sred[8][224];
  __shared__ float qred[8][224];
  const int orig = blockIdx.x;
  const int bi = (orig & 7) * 112 + (orig >> 3);  // exact: 896 = 8 * 112
  const int b = bi / 14, hi = bi % 14;
  const int t = threadIdx.x;
  const float TW = 16.0f / 224.0f;

  const int q = t % 56;
  const int grp = t / 56;     // 0..9; active grp<8
  const int x4 = q * 4;

  int sloff[4];
  {
    int wi = x4 % 14, p2 = x4 / 14;
    #pragma unroll
    for (int j = 0; j < 4; ++j) {
      sloff[j] = wi * 2312 + p2;
      if (++wi == 14) { wi = 0; ++p2; }
    }
  }

  if (grp < 8) {
    f32x4 sAcc = {0.f, 0.f, 0.f, 0.f}, qAcc = {0.f, 0.f, 0.f, 0.f};
    #pragma unroll
    for (int it = 0; it < 6; ++it) {
      const int cp = grp * 6 + it;
      const int c = cp >> 4, p1 = cp & 15;
      const int y = p1 * 14 + hi;
      const float* row = x + ((size_t)(b * 3 + c)) * 50176 + (size_t)y * 224;
      const f32x4 xv = *(const f32x4*)(row + x4);
      f32x4 ra = {0.f,0.f,0.f,0.f}, rb = {0.f,0.f,0.f,0.f};
      f32x4 la = {0.f,0.f,0.f,0.f}, lb = {0.f,0.f,0.f,0.f};
      if (q < 54) {
        ra = *(const f32x4*)(row + x4 + 8);
        if (y < 223) rb = *(const f32x4*)(row + x4 + 8 + 224);
      }
      if (q >= 2) {
        la = *(const f32x4*)(row + x4 - 8);
        if (y > 0) lb = *(const f32x4*)(row + x4 - 8 - 224);
      }
      const f32x4 rv = (1.0f - TW) * ra + TW * rb;
      const f32x4 lv = (1.0f - TW) * la + TW * lb;
      sAcc += xv + 2.0f * (lv + rv);
      qAcc += xv * xv + 2.0f * (lv * lv + rv * rv);
      const int kb = c * 256 + p1 * 16;
      #pragma unroll
      for (int j = 0; j < 4; ++j) {
        slab[sloff[j] + kb]        = f2bf(xv[j]);
        slab[sloff[j] + kb + 768]  = f2bf(lv[j]);
        slab[sloff[j] + kb + 1536] = f2bf(rv[j]);
      }
    }
    #pragma unroll
    for (int j = 0; j < 4; ++j) {
      sred[grp][x4 + j] = sAcc[j];
      qred[grp][x4 + j] = qAcc[j];
    }
  }
  __syncthreads();

  if (t < 224) {
    float ss = 0.f, qq = 0.f;
    #pragma unroll
    for (int g = 0; g < 8; ++g) { ss += sred[g][t]; qq += qred[g][t]; }
    sred[0][t] = ss;  // column-private
    qred[0][t] = qq;
  }
  __syncthreads();

  const int tok0 = b * 196 + hi * 14;
  if (t < 14) {
    float S = 0.f, Q = 0.f;
    #pragma unroll
    for (int p = 0; p < 16; ++p) { S += sred[0][t + 14 * p]; Q += qred[0][t + 14 * p]; }
    const float mu = S / 3840.f;
    const float var = Q / 3840.f - mu * mu;
    const float r = rsqrtf(var + 1e-5f);
    stats[tok0 + t] = make_float2(r, -mu * r);
  }

  for (int i = t; i < 14 * 288; i += 512) {
    const int wi2 = i / 288, off = i % 288;
    *(u16x8*)&V[(size_t)(tok0 + wi2) * 2304 + off * 8] =
        *(const u16x8*)&slab[wi2 * 2312 + off * 8];
  }
}

// ---------------------------------------------------------------------------
// Kernel 4: GEMM  out[m][j] = r_m * (V[m,:] . w2t[j,:]) + (-mu*r)_m * G[j] + Bt[j]
// 224x96 tile, BK=64, 4 waves (2x2, wave 112x48). A: dbuf LDS (56 KiB, XOR
// swizzle, global_load_lds) -> 2 blocks/CU. B: DIRECT global(L2)->register,
// double-buffered named regs, prefetched 1 K-step (~1800cyc >> L2 225cyc).
// Per step VMEM = 7 stage + 6 B-loads -> vmcnt(13). LDS reads/wave-step
// 20 -> 14: LDS pipe (~1600cyc/CU) <= MFMA (1630cyc/SIMD).
// grid 448 = 56m x 8n, exact XCD swizzle, N-fastest (w2t panel L2-hot).
// ---------------------------------------------------------------------------
__global__ __launch_bounds__(256, 2) void spt_gemm(
    const unsigned short* __restrict__ V, const unsigned short* __restrict__ w2t,
    const float2* __restrict__ stats, const float* __restrict__ G,
    const float* __restrict__ Bt, float* __restrict__ out)
{
  __shared__ unsigned short Alds[2][224 * 64];

  const int orig = blockIdx.x;
  const int wgid = (orig & 7) * 56 + (orig >> 3);  // exact: 448 = 8 * 56
  const int m0 = (wgid >> 3) * 224;
  const int n0 = (wgid & 7) * 96;
  const int t = threadIdx.x;
  const int w = t >> 6, l = t & 63;
  const int wr = w >> 1;   // 0..1 -> 112-row half
  const int wn = w & 1;    // 0..1 -> 48-col slice

  f32x4 acc[7][3] = {};

  // B fragment base pointers (per-lane): row = n0+wn*48+n*16+(l&15),
  // column base (l>>4)*8 elems; step offset kt*64 (+32 for kk=1).
  const unsigned short* gBF[3];
  #pragma unroll
  for (int n = 0; n < 3; ++n)
    gBF[n] = w2t + (size_t)(n0 + wn * 48 + n * 16 + (l & 15)) * 2304 + ((l >> 4) << 3);

#define STAGE(pb, kt)                                                          \
  {                                                                            \
    const int k0s = (kt) << 6;                                                 \
    _Pragma("unroll") for (int i = 0; i < 7; ++i) {                            \
      const int c = i * 256 + t;                                               \
      const int row = c >> 3;                                                  \
      const int srcel = (((c & 7) ^ (row & 7)) << 3);                          \
      const unsigned short* ga = V + (size_t)(m0 + row) * 2304 + k0s + srcel;  \
      __builtin_amdgcn_global_load_lds((const GLOBAL_AS unsigned int*)ga,      \
          (LDS_AS unsigned int*)&Alds[pb][i * 2048 + w * 512], 16, 0, 0);      \
    }                                                                          \
  }

#define BLOAD(BF, kt)                                                          \
  {                                                                            \
    const int koff = (kt) << 6;                                                \
    _Pragma("unroll") for (int n = 0; n < 3; ++n) {                            \
      BF##0[n] = *(const bf16x8*)(gBF[n] + koff);                              \
      BF##1[n] = *(const bf16x8*)(gBF[n] + koff + 32);                         \
    }                                                                          \
  }

  // Hoist 14 A-frags into regs, then 42-MFMA burst with reg-resident B.
#define COMPUTE(pb, B0, B1)                                                    \
  {                                                                            \
    const int lane15 = l & 15;                                                 \
    const int kcol = (l >> 4) << 4;                                            \
    bf16x8 aF[2][7];                                                           \
    _Pragma("unroll") for (int kk = 0; kk < 2; ++kk) {                         \
      const int kb = kk * 64 + kcol;                                           \
      _Pragma("unroll") for (int m = 0; m < 7; ++m) {                          \
        const int row = wr * 112 + m * 16 + lane15;                            \
        const int phys = row * 128 + (kb ^ ((row & 7) << 4));                  \
        aF[kk][m] = *(const bf16x8*)&Alds[pb][phys >> 1];                      \
      }                                                                        \
    }                                                                          \
    __builtin_amdgcn_s_setprio(1);                                             \
    _Pragma("unroll") for (int m = 0; m < 7; ++m)                              \
      _Pragma("unroll") for (int n = 0; n < 3; ++n)                            \
        acc[m][n] = __builtin_amdgcn_mfma_f32_16x16x32_bf16(aF[0][m], B0[n],   \
                                                            acc[m][n], 0, 0, 0); \
    _Pragma("unroll") for (int m = 0; m < 7; ++m)                              \
      _Pragma("unroll") for (int n = 0; n < 3; ++n)                            \
        acc[m][n] = __builtin_amdgcn_mfma_f32_16x16x32_bf16(aF[1][m], B1[n],   \
                                                            acc[m][n], 0, 0, 0); \
    __builtin_amdgcn_s_setprio(0);                                             \
  }

  bf16x8 bX0[3], bX1[3], bY0[3], bY1[3];

  STAGE(0, 0);
  BLOAD(bX, 0);
  // 17 double-steps cover kt = 0..33
  for (int i = 0; i < 17; ++i) {
    const int kt = i * 2;
    // step kt (even): read buf0 + bX, issue kt+1 into buf1 + bY
    STAGE(1, kt + 1);
    BLOAD(bY, kt + 1);
    asm volatile("s_waitcnt vmcnt(13)\n\ts_barrier" ::: "memory");
    COMPUTE(0, bX0, bX1);
    asm volatile("s_barrier" ::: "memory");
    // step kt+1 (odd): read buf1 + bY, issue kt+2 into buf0 + bX
    STAGE(0, kt + 2);
    BLOAD(bX, kt + 2);
    asm volatile("s_waitcnt vmcnt(13)\n\ts_barrier" ::: "memory");
    COMPUTE(1, bY0, bY1);
    asm volatile("s_barrier" ::: "memory");
  }
  // step 34: read buf0 + bX, issue 35 into buf1 + bY
  STAGE(1, 35);
  BLOAD(bY, 35);
  asm volatile("s_waitcnt vmcnt(13)\n\ts_barrier" ::: "memory");
  COMPUTE(0, bX0, bX1);
  asm volatile("s_barrier" ::: "memory");
  // step 35: drain and finish
  asm volatile("s_waitcnt vmcnt(0)\n\ts_barrier" ::: "memory");
  COMPUTE(1, bY0, bY1);

  // Epilogue: C/D frag layout col = l&15, row = (l>>4)*4 + reg
  const int lane15 = l & 15;
  const int lg = (l >> 4) * 4;
  #pragma unroll
  for (int m = 0; m < 7; ++m) {
    const int rowb = m0 + wr * 112 + m * 16 + lg;
    float2 st[4];
    #pragma unroll
    for (int r = 0; r < 4; ++r) st[r] = stats[rowb + r];
    #pragma unroll
    for (int n = 0; n < 3; ++n) {
      const int col = n0 + wn * 48 + n * 16 + lane15;
      const float Gc = G[col];
      const float Bc = Bt[col];
      #pragma unroll
      for (int r = 0; r < 4; ++r) {
        out[(size_t)(rowb + r) * 768 + col] = st[r].x * acc[m][n][r] + st[r].y * Gc + Bc;
      }
    }
  }
#undef STAGE
#undef BLOAD
#undef COMPUTE
}

// ---------------------------------------------------------------------------
// Workspace layout (bytes):
//   V     : 0            57,802,752
//   w2t   : 57,802,752    3,538,944
//   stats : 61,341,696      100,352
//   G     : 61,442,048        3,072
//   Bt    : 61,445,120        3,072
//   Gp    : 61,448,192      442,368
//   Bp    : 61,890,560      442,368   -> total 62,332,928
// ---------------------------------------------------------------------------
extern "C" void kernel_launch(void* const* d_in, const int* in_sizes, int n_in,
                              void* d_out, int out_size, void* d_ws, size_t ws_size,
                              hipStream_t stream) {
  const float* x     = (const float*)d_in[0];
  const float* gamma = (const float*)d_in[1];
  const float* beta  = (const float*)d_in[2];
  const float* w     = (const float*)d_in[3];
  const float* bvec  = (const float*)d_in[4];
  float* out = (float*)d_out;

  char* ws = (char*)d_ws;
  unsigned short* V   = (unsigned short*)(ws);
  unsigned short* w2t = (unsigned short*)(ws + 57802752);
  float2* stats       = (float2*)(ws + 61341696);
  float* G            = (float*)(ws + 61442048);
  float* Bt           = (float*)(ws + 61445120);
  float* Gp           = (float*)(ws + 61448192);
  float* Bp           = (float*)(ws + 61890560);

  spt_pack<<<896, 512, 0, stream>>>(x, V, stats);
  spt_fold_w<<<dim3(144, 3), 256, 0, stream>>>(gamma, beta, w, w2t, Gp, Bp);
  spt_gb<<<3, 256, 0, stream>>>(Gp, Bp, bvec, G, Bt);
  spt_gemm<<<448, 256, 0, stream>>>(V, w2t, stats, G, Bt, out);
}

// Round 11
// 95.592 us; speedup vs baseline: 1.2247x; 1.2247x over previous
//
#include <hip/hip_runtime.h>

// ShiftedPatchTokenization on MI355X (gfx950)
// x[64,3,224,224] f32 -> out[64,196,768] f32
// fold_w (frag-order w2f + G/Bt partials) -> gb -> pack -> 128x192 GEMM:
// A via dbuf LDS, B via COALESCED fragment-order loads from L2 (no B in LDS).

typedef short bf16x8 __attribute__((ext_vector_type(8)));
typedef unsigned short u16x8 __attribute__((ext_vector_type(8)));
typedef float f32x4 __attribute__((ext_vector_type(4)));

#define GLOBAL_AS __attribute__((address_space(1)))
#define LDS_AS __attribute__((address_space(3)))

__device__ __forceinline__ unsigned short f2bf(float f) {
  union { float f; unsigned int u; } v;
  v.f = f;
  unsigned int u = v.u;
  unsigned int r = (u + 0x7FFFu + ((u >> 16) & 1u)) >> 16;  // RNE
  return (unsigned short)r;
}

// ---------------------------------------------------------------------------
// Kernel 1: fold gamma*w over duplicated shift groups, store in MFMA-fragment
// order: w2f[(g*72 + c)*512 + ch*128 + (j&15)*8 + e]  where g=j>>4, c=k>>5,
// ch=(k>>3)&3, e=k&7.  A wave's B-fragment (16 rows x 8 k for lane-chunk) is
// then 1 KiB CONTIGUOUS -> one coalesced global_load_dwordx4 per fragment.
// Also emits per-f2-block partial sums for G/Bt. grid (144, 3), block 256
// ---------------------------------------------------------------------------
__global__ __launch_bounds__(256) void spt_fold_w(
    const float* __restrict__ gamma, const float* __restrict__ beta,
    const float* __restrict__ w, unsigned short* __restrict__ w2f,
    float* __restrict__ Gp, float* __restrict__ Bp)
{
  __shared__ float tile[16][257];
  const int f2blk = blockIdx.x * 16;
  const int jblk  = blockIdx.y * 256;
  const int t = threadIdx.x;
  const int j = jblk + t;
  float gacc = 0.f, bacc = 0.f;
  #pragma unroll
  for (int i = 0; i < 16; ++i) {
    const int f2 = f2blk + i;
    const int g = f2 / 768;
    const int rem = f2 % 768;  // c*256 + p1*16 + p2
    float v, bv;
    if (g == 0) {
      const int f = rem;
      const float wv = w[(size_t)f * 768 + j];
      v = gamma[f] * wv;
      bv = beta[f] * wv;
    } else if (g == 1) {
      const int fa = 768 + rem, fb = 2304 + rem;   // left_up, left_down
      const float wa = w[(size_t)fa * 768 + j], wb = w[(size_t)fb * 768 + j];
      v = gamma[fa] * wa + gamma[fb] * wb;
      bv = beta[fa] * wa + beta[fb] * wb;
    } else {
      const int fa = 1536 + rem, fb = 3072 + rem;  // right_up, right_down
      const float wa = w[(size_t)fa * 768 + j], wb = w[(size_t)fb * 768 + j];
      v = gamma[fa] * wa + gamma[fb] * wb;
      bv = beta[fa] * wa + beta[fb] * wb;
    }
    tile[i][t] = v;
    gacc += v;
    bacc += bv;
  }
  __syncthreads();
  u16x8 lo, hi;
  #pragma unroll
  for (int i = 0; i < 8; ++i) {
    lo[i] = f2bf(tile[i][t]);      // k = f2blk + i
    hi[i] = f2bf(tile[8 + i][t]);  // k = f2blk + 8 + i
  }
  const int grp = j >> 4;
  const int c32 = f2blk >> 5;
  const int ch  = (f2blk >> 3) & 3;  // 0 or 2 (f2blk is 16-aligned)
  unsigned short* dst = w2f + ((size_t)(grp * 72 + c32)) * 512 + ch * 128 + (j & 15) * 8;
  *(u16x8*)dst = lo;
  *(u16x8*)(dst + 128) = hi;
  Gp[blockIdx.x * 768 + j] = gacc;
  Bp[blockIdx.x * 768 + j] = bacc;
}

// ---------------------------------------------------------------------------
// Kernel 2: reduce 144 partials -> G[768], Bt[768] (+b). grid 3, block 256
// ---------------------------------------------------------------------------
__global__ __launch_bounds__(256) void spt_gb(
    const float* __restrict__ Gp, const float* __restrict__ Bp,
    const float* __restrict__ bvec, float* __restrict__ G, float* __restrict__ Bt)
{
  const int j = blockIdx.x * 256 + threadIdx.x;
  float g = 0.f, bb = 0.f;
  for (int i = 0; i < 144; ++i) {
    g += Gp[i * 768 + j];
    bb += Bp[i * 768 + j];
  }
  G[j] = g;
  Bt[j] = bb + bvec[j];
}

// ---------------------------------------------------------------------------
// Kernel 3: pack V[12544][2304] bf16 + per-token LN stats (r, -mu*r)
// 512 threads, XCD chunk swizzle (896 = 8*112). grid 896.
// ---------------------------------------------------------------------------
__global__ __launch_bounds__(512) void spt_pack(
    const float* __restrict__ x, unsigned short* __restrict__ V,
    float2* __restrict__ stats)
{
  __shared__ unsigned short slab[14 * 2312];  // token-major, +8 pad per row
  __shared__ float sred[8][224];
  __shared__ float qred[8][224];
  const int orig = blockIdx.x;
  const int bi = (orig & 7) * 112 + (orig >> 3);  // exact: 896 = 8 * 112
  const int b = bi / 14, hi = bi % 14;
  const int t = threadIdx.x;
  const float TW = 16.0f / 224.0f;

  const int q = t % 56;
  const int grp = t / 56;     // 0..9; active grp<8
  const int x4 = q * 4;

  int sloff[4];
  {
    int wi = x4 % 14, p2 = x4 / 14;
    #pragma unroll
    for (int j = 0; j < 4; ++j) {
      sloff[j] = wi * 2312 + p2;
      if (++wi == 14) { wi = 0; ++p2; }
    }
  }

  if (grp < 8) {
    f32x4 sAcc = {0.f, 0.f, 0.f, 0.f}, qAcc = {0.f, 0.f, 0.f, 0.f};
    #pragma unroll
    for (int it = 0; it < 6; ++it) {
      const int cp = grp * 6 + it;
      const int c = cp >> 4, p1 = cp & 15;
      const int y = p1 * 14 + hi;
      const float* row = x + ((size_t)(b * 3 + c)) * 50176 + (size_t)y * 224;
      const f32x4 xv = *(const f32x4*)(row + x4);
      f32x4 ra = {0.f,0.f,0.f,0.f}, rb = {0.f,0.f,0.f,0.f};
      f32x4 la = {0.f,0.f,0.f,0.f}, lb = {0.f,0.f,0.f,0.f};
      if (q < 54) {
        ra = *(const f32x4*)(row + x4 + 8);
        if (y < 223) rb = *(const f32x4*)(row + x4 + 8 + 224);
      }
      if (q >= 2) {
        la = *(const f32x4*)(row + x4 - 8);
        if (y > 0) lb = *(const f32x4*)(row + x4 - 8 - 224);
      }
      const f32x4 rv = (1.0f - TW) * ra + TW * rb;
      const f32x4 lv = (1.0f - TW) * la + TW * lb;
      sAcc += xv + 2.0f * (lv + rv);
      qAcc += xv * xv + 2.0f * (lv * lv + rv * rv);
      const int kb = c * 256 + p1 * 16;
      #pragma unroll
      for (int j = 0; j < 4; ++j) {
        slab[sloff[j] + kb]        = f2bf(xv[j]);
        slab[sloff[j] + kb + 768]  = f2bf(lv[j]);
        slab[sloff[j] + kb + 1536] = f2bf(rv[j]);
      }
    }
    #pragma unroll
    for (int j = 0; j < 4; ++j) {
      sred[grp][x4 + j] = sAcc[j];
      qred[grp][x4 + j] = qAcc[j];
    }
  }
  __syncthreads();

  if (t < 224) {
    float ss = 0.f, qq = 0.f;
    #pragma unroll
    for (int g = 0; g < 8; ++g) { ss += sred[g][t]; qq += qred[g][t]; }
    sred[0][t] = ss;  // column-private
    qred[0][t] = qq;
  }
  __syncthreads();

  const int tok0 = b * 196 + hi * 14;
  if (t < 14) {
    float S = 0.f, Q = 0.f;
    #pragma unroll
    for (int p = 0; p < 16; ++p) { S += sred[0][t + 14 * p]; Q += qred[0][t + 14 * p]; }
    const float mu = S / 3840.f;
    const float var = Q / 3840.f - mu * mu;
    const float r = rsqrtf(var + 1e-5f);
    stats[tok0 + t] = make_float2(r, -mu * r);
  }

  for (int i = t; i < 14 * 288; i += 512) {
    const int wi2 = i / 288, off = i % 288;
    *(u16x8*)&V[(size_t)(tok0 + wi2) * 2304 + off * 8] =
        *(const u16x8*)&slab[wi2 * 2312 + off * 8];
  }
}

// ---------------------------------------------------------------------------
// Kernel 4: GEMM  out[m][j] = r_m * (V[m,:] . w2f[j,:]) + (-mu*r)_m * G[j] + Bt[j]
// 128x192 tile, BK=64, 4 waves (2x2, wave 64x96 = 4x6 frags).
// A: dbuf LDS 32 KiB (XOR swizzle, global_load_lds) -> 2 blocks/CU.
// B: fragment-order w2f, one coalesced 1 KiB load per fragment per wave,
//    L2-resident (3.5 MB/XCD), dbuf in named regs, prefetched 1 K-step.
// Per-CU K-step: LDS ~1000cyc < MFMA 1863cyc -> matrix pipe finally binding.
// Per step VMEM = 4 stage + 12 B -> vmcnt(16). Sync structure = proven r4.
// grid 392 = 98m x 4n, exact XCD chunking (49/XCD), N-fastest.
// ---------------------------------------------------------------------------
__global__ __launch_bounds__(256, 2) void spt_gemm(
    const unsigned short* __restrict__ V, const unsigned short* __restrict__ w2f,
    const float2* __restrict__ stats, const float* __restrict__ G,
    const float* __restrict__ Bt, float* __restrict__ out)
{
  __shared__ unsigned short Alds[2][128 * 64];

  const int orig = blockIdx.x;
  const int wgid = (orig & 7) * 49 + (orig >> 3);  // exact: 392 = 8 * 49
  const int m0 = (wgid >> 2) * 128;
  const int n0 = (wgid & 3) * 192;
  const int t = threadIdx.x;
  const int w = t >> 6, l = t & 63;
  const int wr = w >> 1;   // 0..1 -> 64-row half
  const int wn = w & 1;    // 0..1 -> 96-col half

  f32x4 acc[4][6] = {};

  // B fragment pointers: frag (g, c32) at w2f + (g*72 + c32)*512 + l*8
  const int gbase = (n0 >> 4) + wn * 6;
  const unsigned short* pB[6];
  #pragma unroll
  for (int n = 0; n < 6; ++n)
    pB[n] = w2f + (size_t)(gbase + n) * 36864 + l * 8;

#define STAGE(pb, kt)                                                          \
  {                                                                            \
    const int k0s = (kt) << 6;                                                 \
    _Pragma("unroll") for (int i = 0; i < 4; ++i) {                            \
      const int c = i * 256 + t;                                               \
      const int row = c >> 3;                                                  \
      const int srcel = (((c & 7) ^ (row & 7)) << 3);                          \
      const unsigned short* ga = V + (size_t)(m0 + row) * 2304 + k0s + srcel;  \
      __builtin_amdgcn_global_load_lds((const GLOBAL_AS unsigned int*)ga,      \
          (LDS_AS unsigned int*)&Alds[pb][c * 8], 16, 0, 0);                   \
    }                                                                          \
  }

#define BLOAD(B0, B1, kt)                                                      \
  _Pragma("unroll") for (int n = 0; n < 6; ++n) {                              \
    B0[n] = *(const bf16x8*)(pB[n] + (kt) * 1024);                             \
    B1[n] = *(const bf16x8*)(pB[n] + (kt) * 1024 + 512);                       \
  }

#define COMPUTE(pb, B0, B1)                                                    \
  {                                                                            \
    const int lane15 = l & 15;                                                 \
    const int kcol = (l >> 4) << 4;                                            \
    bf16x8 aF[4];                                                              \
    _Pragma("unroll") for (int m = 0; m < 4; ++m) {                            \
      const int row = wr * 64 + m * 16 + lane15;                               \
      const int phys = row * 128 + (kcol ^ ((row & 7) << 4));                  \
      aF[m] = *(const bf16x8*)&Alds[pb][phys >> 1];                            \
    }                                                                          \
    __builtin_amdgcn_s_setprio(1);                                             \
    _Pragma("unroll") for (int m = 0; m < 4; ++m)                              \
      _Pragma("unroll") for (int n = 0; n < 6; ++n)                            \
        acc[m][n] = __builtin_amdgcn_mfma_f32_16x16x32_bf16(aF[m], B0[n],      \
                                                            acc[m][n], 0, 0, 0); \
    __builtin_amdgcn_s_setprio(0);                                             \
    _Pragma("unroll") for (int m = 0; m < 4; ++m) {                            \
      const int row = wr * 64 + m * 16 + lane15;                               \
      const int phys = row * 128 + ((64 + kcol) ^ ((row & 7) << 4));           \
      aF[m] = *(const bf16x8*)&Alds[pb][phys >> 1];                            \
    }                                                                          \
    __builtin_amdgcn_s_setprio(1);                                             \
    _Pragma("unroll") for (int m = 0; m < 4; ++m)                              \
      _Pragma("unroll") for (int n = 0; n < 6; ++n)                            \
        acc[m][n] = __builtin_amdgcn_mfma_f32_16x16x32_bf16(aF[m], B1[n],      \
                                                            acc[m][n], 0, 0, 0); \
    __builtin_amdgcn_s_setprio(0);                                             \
  }

  bf16x8 bX0[6], bX1[6], bY0[6], bY1[6];

  STAGE(0, 0);
  BLOAD(bX0, bX1, 0);
  // 17 double-steps cover kt = 0..33
  for (int i = 0; i < 17; ++i) {
    const int kt = i * 2;
    STAGE(1, kt + 1);
    BLOAD(bY0, bY1, kt + 1);
    asm volatile("s_waitcnt vmcnt(16)\n\ts_barrier" ::: "memory");
    COMPUTE(0, bX0, bX1);
    asm volatile("s_barrier" ::: "memory");
    STAGE(0, kt + 2);
    BLOAD(bX0, bX1, kt + 2);
    asm volatile("s_waitcnt vmcnt(16)\n\ts_barrier" ::: "memory");
    COMPUTE(1, bY0, bY1);
    asm volatile("s_barrier" ::: "memory");
  }
  // step 34
  STAGE(1, 35);
  BLOAD(bY0, bY1, 35);
  asm volatile("s_waitcnt vmcnt(16)\n\ts_barrier" ::: "memory");
  COMPUTE(0, bX0, bX1);
  asm volatile("s_barrier" ::: "memory");
  // step 35: drain and finish
  asm volatile("s_waitcnt vmcnt(0)\n\ts_barrier" ::: "memory");
  COMPUTE(1, bY0, bY1);

  // Epilogue: C/D frag layout col = l&15, row = (l>>4)*4 + reg
  const int lane15 = l & 15;
  const int lg = (l >> 4) * 4;
  #pragma unroll
  for (int m = 0; m < 4; ++m) {
    const int rowb = m0 + wr * 64 + m * 16 + lg;
    float2 st[4];
    #pragma unroll
    for (int r = 0; r < 4; ++r) st[r] = stats[rowb + r];
    #pragma unroll
    for (int n = 0; n < 6; ++n) {
      const int col = n0 + wn * 96 + n * 16 + lane15;
      const float Gc = G[col];
      const float Bc = Bt[col];
      #pragma unroll
      for (int r = 0; r < 4; ++r) {
        out[(size_t)(rowb + r) * 768 + col] = st[r].x * acc[m][n][r] + st[r].y * Gc + Bc;
      }
    }
  }
#undef STAGE
#undef BLOAD
#undef COMPUTE
}

// ---------------------------------------------------------------------------
// Workspace layout (bytes):
//   V     : 0            57,802,752
//   w2f   : 57,802,752    3,538,944   (fragment-order folded weights)
//   stats : 61,341,696      100,352
//   G     : 61,442,048        3,072
//   Bt    : 61,445,120        3,072
//   Gp    : 61,448,192      442,368
//   Bp    : 61,890,560      442,368   -> total 62,332,928
// ---------------------------------------------------------------------------
extern "C" void kernel_launch(void* const* d_in, const int* in_sizes, int n_in,
                              void* d_out, int out_size, void* d_ws, size_t ws_size,
                              hipStream_t stream) {
  const float* x     = (const float*)d_in[0];
  const float* gamma = (const float*)d_in[1];
  const float* beta  = (const float*)d_in[2];
  const float* w     = (const float*)d_in[3];
  const float* bvec  = (const float*)d_in[4];
  float* out = (float*)d_out;

  char* ws = (char*)d_ws;
  unsigned short* V   = (unsigned short*)(ws);
  unsigned short* w2f = (unsigned short*)(ws + 57802752);
  float2* stats       = (float2*)(ws + 61341696);
  float* G            = (float*)(ws + 61442048);
  float* Bt           = (float*)(ws + 61445120);
  float* Gp           = (float*)(ws + 61448192);
  float* Bp           = (float*)(ws + 61890560);

  spt_pack<<<896, 512, 0, stream>>>(x, V, stats);
  spt_fold_w<<<dim3(144, 3), 256, 0, stream>>>(gamma, beta, w, w2f, Gp, Bp);
  spt_gb<<<3, 256, 0, stream>>>(Gp, Bp, bvec, G, Bt);
  spt_gemm<<<392, 256, 0, stream>>>(V, w2f, stats, G, Bt, out);
}

// Round 12
// 91.842 us; speedup vs baseline: 1.2747x; 1.0408x over previous
//
#include <hip/hip_runtime.h>

// ShiftedPatchTokenization on MI355X (gfx950)
// x[64,3,224,224] f32 -> out[64,196,768] f32
// fold_w (+G/Bt partials) -> gb -> pack -> 224x192 8-wave m201-rhythm GEMM:
// 4 phases/K-tile, triple-buffered LDS, counted vmcnt at phase ends.

typedef short bf16x8 __attribute__((ext_vector_type(8)));
typedef unsigned short u16x8 __attribute__((ext_vector_type(8)));
typedef float f32x4 __attribute__((ext_vector_type(4)));

#define GLOBAL_AS __attribute__((address_space(1)))
#define LDS_AS __attribute__((address_space(3)))

__device__ __forceinline__ unsigned short f2bf(float f) {
  union { float f; unsigned int u; } v;
  v.f = f;
  unsigned int u = v.u;
  unsigned int r = (u + 0x7FFFu + ((u >> 16) & 1u)) >> 16;  // RNE
  return (unsigned short)r;
}

// ---------------------------------------------------------------------------
// Kernel 1: fold gamma*w -> w2t[768][2304] bf16 (row-major) + G/Bt partials.
// grid (144, 3), block 256
// ---------------------------------------------------------------------------
__global__ __launch_bounds__(256) void spt_fold_w(
    const float* __restrict__ gamma, const float* __restrict__ beta,
    const float* __restrict__ w, unsigned short* __restrict__ w2t,
    float* __restrict__ Gp, float* __restrict__ Bp)
{
  __shared__ float tile[16][257];
  const int f2blk = blockIdx.x * 16;
  const int jblk  = blockIdx.y * 256;
  const int t = threadIdx.x;
  const int j = jblk + t;
  float gacc = 0.f, bacc = 0.f;
  #pragma unroll
  for (int i = 0; i < 16; ++i) {
    const int f2 = f2blk + i;
    const int g = f2 / 768;
    const int rem = f2 % 768;
    float v, bv;
    if (g == 0) {
      const int f = rem;
      const float wv = w[(size_t)f * 768 + j];
      v = gamma[f] * wv;
      bv = beta[f] * wv;
    } else if (g == 1) {
      const int fa = 768 + rem, fb = 2304 + rem;
      const float wa = w[(size_t)fa * 768 + j], wb = w[(size_t)fb * 768 + j];
      v = gamma[fa] * wa + gamma[fb] * wb;
      bv = beta[fa] * wa + beta[fb] * wb;
    } else {
      const int fa = 1536 + rem, fb = 3072 + rem;
      const float wa = w[(size_t)fa * 768 + j], wb = w[(size_t)fb * 768 + j];
      v = gamma[fa] * wa + gamma[fb] * wb;
      bv = beta[fa] * wa + beta[fb] * wb;
    }
    tile[i][t] = v;
    gacc += v;
    bacc += bv;
  }
  __syncthreads();
  u16x8 lo, hi;
  #pragma unroll
  for (int i = 0; i < 8; ++i) {
    lo[i] = f2bf(tile[i][t]);
    hi[i] = f2bf(tile[8 + i][t]);
  }
  unsigned short* dst = w2t + (size_t)j * 2304 + f2blk;
  *(u16x8*)dst = lo;
  *(u16x8*)(dst + 8) = hi;
  Gp[blockIdx.x * 768 + j] = gacc;
  Bp[blockIdx.x * 768 + j] = bacc;
}

// ---------------------------------------------------------------------------
// Kernel 2: reduce partials -> G, Bt. grid 3, block 256
// ---------------------------------------------------------------------------
__global__ __launch_bounds__(256) void spt_gb(
    const float* __restrict__ Gp, const float* __restrict__ Bp,
    const float* __restrict__ bvec, float* __restrict__ G, float* __restrict__ Bt)
{
  const int j = blockIdx.x * 256 + threadIdx.x;
  float g = 0.f, bb = 0.f;
  for (int i = 0; i < 144; ++i) {
    g += Gp[i * 768 + j];
    bb += Bp[i * 768 + j];
  }
  G[j] = g;
  Bt[j] = bb + bvec[j];
}

// ---------------------------------------------------------------------------
// Kernel 3: pack V + LN stats. 512 threads, XCD swizzle. grid 896.
// ---------------------------------------------------------------------------
__global__ __launch_bounds__(512) void spt_pack(
    const float* __restrict__ x, unsigned short* __restrict__ V,
    float2* __restrict__ stats)
{
  __shared__ unsigned short slab[14 * 2312];
  __shared__ float sred[8][224];
  __shared__ float qred[8][224];
  const int orig = blockIdx.x;
  const int bi = (orig & 7) * 112 + (orig >> 3);  // 896 = 8*112
  const int b = bi / 14, hi = bi % 14;
  const int t = threadIdx.x;
  const float TW = 16.0f / 224.0f;

  const int q = t % 56;
  const int grp = t / 56;
  const int x4 = q * 4;

  int sloff[4];
  {
    int wi = x4 % 14, p2 = x4 / 14;
    #pragma unroll
    for (int j = 0; j < 4; ++j) {
      sloff[j] = wi * 2312 + p2;
      if (++wi == 14) { wi = 0; ++p2; }
    }
  }

  if (grp < 8) {
    f32x4 sAcc = {0.f, 0.f, 0.f, 0.f}, qAcc = {0.f, 0.f, 0.f, 0.f};
    #pragma unroll
    for (int it = 0; it < 6; ++it) {
      const int cp = grp * 6 + it;
      const int c = cp >> 4, p1 = cp & 15;
      const int y = p1 * 14 + hi;
      const float* row = x + ((size_t)(b * 3 + c)) * 50176 + (size_t)y * 224;
      const f32x4 xv = *(const f32x4*)(row + x4);
      f32x4 ra = {0.f,0.f,0.f,0.f}, rb = {0.f,0.f,0.f,0.f};
      f32x4 la = {0.f,0.f,0.f,0.f}, lb = {0.f,0.f,0.f,0.f};
      if (q < 54) {
        ra = *(const f32x4*)(row + x4 + 8);
        if (y < 223) rb = *(const f32x4*)(row + x4 + 8 + 224);
      }
      if (q >= 2) {
        la = *(const f32x4*)(row + x4 - 8);
        if (y > 0) lb = *(const f32x4*)(row + x4 - 8 - 224);
      }
      const f32x4 rv = (1.0f - TW) * ra + TW * rb;
      const f32x4 lv = (1.0f - TW) * la + TW * lb;
      sAcc += xv + 2.0f * (lv + rv);
      qAcc += xv * xv + 2.0f * (lv * lv + rv * rv);
      const int kb = c * 256 + p1 * 16;
      #pragma unroll
      for (int j = 0; j < 4; ++j) {
        slab[sloff[j] + kb]        = f2bf(xv[j]);
        slab[sloff[j] + kb + 768]  = f2bf(lv[j]);
        slab[sloff[j] + kb + 1536] = f2bf(rv[j]);
      }
    }
    #pragma unroll
    for (int j = 0; j < 4; ++j) {
      sred[grp][x4 + j] = sAcc[j];
      qred[grp][x4 + j] = qAcc[j];
    }
  }
  __syncthreads();

  if (t < 224) {
    float ss = 0.f, qq = 0.f;
    #pragma unroll
    for (int g = 0; g < 8; ++g) { ss += sred[g][t]; qq += qred[g][t]; }
    sred[0][t] = ss;
    qred[0][t] = qq;
  }
  __syncthreads();

  const int tok0 = b * 196 + hi * 14;
  if (t < 14) {
    float S = 0.f, Q = 0.f;
    #pragma unroll
    for (int p = 0; p < 16; ++p) { S += sred[0][t + 14 * p]; Q += qred[0][t + 14 * p]; }
    const float mu = S / 3840.f;
    const float var = Q / 3840.f - mu * mu;
    const float r = rsqrtf(var + 1e-5f);
    stats[tok0 + t] = make_float2(r, -mu * r);
  }

  for (int i = t; i < 14 * 288; i += 512) {
    const int wi2 = i / 288, off = i % 288;
    *(u16x8*)&V[(size_t)(tok0 + wi2) * 2304 + off * 8] =
        *(const u16x8*)&slab[wi2 * 2312 + off * 8];
  }
}

// ---------------------------------------------------------------------------
// Kernel 4: GEMM, m201-rhythm. 224x192 tile, BK=64, 512 thr / 8 waves
// (2M x 4N, wave 112x48 = 7x3 frags). 4 phases per K-tile:
//  ph0 {rd A0-3,B k0 | stage-slice | bar | lgkm0 | prio1 12-MFMA prio0 | bar}
//  ph1 {rd A4-6  k0  | stage-slice | bar | lgkm0 | prio1  9-MFMA prio0 | bar}
//  ph2 {rd A0-3,B k1 |             | bar | lgkm0 | prio1 12-MFMA prio0 | bar}
//  ph3 {rd A4-6  k1  | VMCNT(7|6)  | bar | lgkm0 | prio1  9-MFMA prio0 | bar}
// Counted vmcnt at phase ENDS (3,7) so the trailing barrier is the collective
// cert point; stage(t+2) issued ph0-1, stage(t+3) ph4-5 (ages 6-8 phases >>
// HBM latency). Triple-buffered 156 KiB LDS, static buf indices (3-pair
// unroll). A-waves (0-3) stage A (7 loads), B-waves (4-7) stage B (6).
// XOR swizzle w/ pre-swizzled source (proven conflict-free).
// grid 224 = 56m x 4n, exact XCD chunking (28/XCD), N-fastest.
// ---------------------------------------------------------------------------
__global__ __launch_bounds__(512, 1) void spt_gemm(
    const unsigned short* __restrict__ V, const unsigned short* __restrict__ w2t,
    const float2* __restrict__ stats, const float* __restrict__ G,
    const float* __restrict__ Bt, float* __restrict__ out)
{
  __shared__ unsigned short Al[3][224 * 64];  // 28672 B each
  __shared__ unsigned short Bl[3][192 * 64];  // 24576 B each  -> 156 KiB total

  const int orig = blockIdx.x;
  const int wgid = (orig & 7) * 28 + (orig >> 3);  // exact: 224 = 8*28
  const int m0 = (wgid >> 2) * 224;
  const int n0 = (wgid & 3) * 192;
  const int t = threadIdx.x;
  const int w = t >> 6, l = t & 63;
  const int wr = w >> 2;   // 0..1 -> 112-row half
  const int wn = w & 3;    // 0..3 -> 48-col slice
  const bool isA = (w < 4);
  const int ts = isA ? t : (t - 256);

  f32x4 acc[7][3] = {};
  bf16x8 aF[4], aG[3], bF[3];

  const int lane15 = l & 15;
  const int kcol = (l >> 4) << 4;  // byte offset of lane-group within 64B half
  const int srow = ts >> 3;
  const int srcel = (((ts & 7) ^ ((ts >> 3) & 7)) << 3);

#define STG1(P, kt)                                                            \
  if (isA) {                                                                   \
    _Pragma("unroll") for (int i = 0; i < 4; ++i)                              \
      __builtin_amdgcn_global_load_lds(                                        \
        (const GLOBAL_AS unsigned int*)(V + (size_t)(m0 + i * 32 + srow) * 2304 + (kt) * 64 + srcel), \
        (LDS_AS unsigned int*)&Al[P][(i * 256 + ts) * 8], 16, 0, 0);           \
  } else {                                                                     \
    _Pragma("unroll") for (int i = 0; i < 3; ++i)                              \
      __builtin_amdgcn_global_load_lds(                                        \
        (const GLOBAL_AS unsigned int*)(w2t + (size_t)(n0 + i * 32 + srow) * 2304 + (kt) * 64 + srcel), \
        (LDS_AS unsigned int*)&Bl[P][(i * 256 + ts) * 8], 16, 0, 0);           \
  }
#define STG2(P, kt)                                                            \
  if (isA) {                                                                   \
    _Pragma("unroll") for (int i = 4; i < 7; ++i)                              \
      __builtin_amdgcn_global_load_lds(                                        \
        (const GLOBAL_AS unsigned int*)(V + (size_t)(m0 + i * 32 + srow) * 2304 + (kt) * 64 + srcel), \
        (LDS_AS unsigned int*)&Al[P][(i * 256 + ts) * 8], 16, 0, 0);           \
  } else {                                                                     \
    _Pragma("unroll") for (int i = 3; i < 6; ++i)                              \
      __builtin_amdgcn_global_load_lds(                                        \
        (const GLOBAL_AS unsigned int*)(w2t + (size_t)(n0 + i * 32 + srow) * 2304 + (kt) * 64 + srcel), \
        (LDS_AS unsigned int*)&Bl[P][(i * 256 + ts) * 8], 16, 0, 0);           \
  }

#define RA03(P, kh)                                                            \
  _Pragma("unroll") for (int mi = 0; mi < 4; ++mi) {                           \
    const int row = wr * 112 + mi * 16 + lane15;                               \
    const int phys = row * 128 + (((kh) + kcol) ^ ((row & 7) << 4));           \
    aF[mi] = *(const bf16x8*)&Al[P][phys >> 1];                                \
  }
#define RA46(P, kh)                                                            \
  _Pragma("unroll") for (int mi = 0; mi < 3; ++mi) {                           \
    const int row = wr * 112 + (mi + 4) * 16 + lane15;                         \
    const int phys = row * 128 + (((kh) + kcol) ^ ((row & 7) << 4));           \
    aG[mi] = *(const bf16x8*)&Al[P][phys >> 1];                                \
  }
#define RB(P, kh)                                                              \
  _Pragma("unroll") for (int ni = 0; ni < 3; ++ni) {                           \
    const int row = wn * 48 + ni * 16 + lane15;                                \
    const int phys = row * 128 + (((kh) + kcol) ^ ((row & 7) << 4));           \
    bF[ni] = *(const bf16x8*)&Bl[P][phys >> 1];                                \
  }

#define M03                                                                    \
  _Pragma("unroll") for (int mi = 0; mi < 4; ++mi)                             \
    _Pragma("unroll") for (int ni = 0; ni < 3; ++ni)                           \
      acc[mi][ni] = __builtin_amdgcn_mfma_f32_16x16x32_bf16(aF[mi], bF[ni], acc[mi][ni], 0, 0, 0);
#define M46                                                                    \
  _Pragma("unroll") for (int mi = 0; mi < 3; ++mi)                             \
    _Pragma("unroll") for (int ni = 0; ni < 3; ++ni)                           \
      acc[mi + 4][ni] = __builtin_amdgcn_mfma_f32_16x16x32_bf16(aG[mi], bF[ni], acc[mi + 4][ni], 0, 0, 0);

#define BARLG asm volatile("s_barrier\n\ts_waitcnt lgkmcnt(0)" ::: "memory")
#define BARE  asm volatile("s_barrier" ::: "memory")
#define PR1 __builtin_amdgcn_s_setprio(1)
#define PR0 __builtin_amdgcn_s_setprio(0)
#define VMC                                                                    \
  if (isA) asm volatile("s_waitcnt vmcnt(7)" ::: "memory");                    \
  else     asm volatile("s_waitcnt vmcnt(6)" ::: "memory");

#define PAIR(bA, bB, bS2, bS3, t2, t3)                                         \
  RA03(bA, 0);  RB(bA, 0);  STG1(bS2, t2); BARLG; PR1; M03; PR0; BARE;         \
  RA46(bA, 0);              STG2(bS2, t2); BARLG; PR1; M46; PR0; BARE;         \
  RA03(bA, 64); RB(bA, 64);                BARLG; PR1; M03; PR0; BARE;         \
  RA46(bA, 64);             VMC;           BARLG; PR1; M46; PR0; BARE;         \
  RA03(bB, 0);  RB(bB, 0);  STG1(bS3, t3); BARLG; PR1; M03; PR0; BARE;         \
  RA46(bB, 0);              STG2(bS3, t3); BARLG; PR1; M46; PR0; BARE;         \
  RA03(bB, 64); RB(bB, 64);                BARLG; PR1; M03; PR0; BARE;         \
  RA46(bB, 64);             VMC;           BARLG; PR1; M46; PR0; BARE;

  // Prologue: stage tiles 0, 1; certify tile 0 (leave tile 1 in flight).
  STG1(0, 0); STG2(0, 0);
  STG1(1, 1); STG2(1, 1);
  VMC;
  BARE;

  for (int i = 0; i < 5; ++i) {
    const int b = 6 * i;
    PAIR(0, 1, 2, 0, b + 2, b + 3)
    PAIR(2, 0, 1, 2, b + 4, b + 5)
    PAIR(1, 2, 0, 1, b + 6, b + 7)
  }
  PAIR(0, 1, 2, 0, 32, 33)   // pair 15: tiles 30,31
  PAIR(2, 0, 1, 2, 34, 35)   // pair 16: tiles 32,33

  // last pair: tiles 34 (buf1), 35 (buf2); no staging
  RA03(1, 0);  RB(1, 0);  BARLG; PR1; M03; PR0; BARE;
  RA46(1, 0);             BARLG; PR1; M46; PR0; BARE;
  RA03(1, 64); RB(1, 64); BARLG; PR1; M03; PR0; BARE;
  RA46(1, 64); asm volatile("s_waitcnt vmcnt(0)" ::: "memory");
                          BARLG; PR1; M46; PR0; BARE;
  RA03(2, 0);  RB(2, 0);  BARLG; PR1; M03; PR0; BARE;
  RA46(2, 0);             BARLG; PR1; M46; PR0; BARE;
  RA03(2, 64); RB(2, 64); BARLG; PR1; M03; PR0; BARE;
  RA46(2, 64);            asm volatile("s_waitcnt lgkmcnt(0)" ::: "memory");
                          PR1; M46; PR0;

  // Epilogue: C/D frag layout col = l&15, row = (l>>4)*4 + reg
  const int lg = (l >> 4) * 4;
  #pragma unroll
  for (int m = 0; m < 7; ++m) {
    const int rowb = m0 + wr * 112 + m * 16 + lg;
    float2 st[4];
    #pragma unroll
    for (int r = 0; r < 4; ++r) st[r] = stats[rowb + r];
    #pragma unroll
    for (int n = 0; n < 3; ++n) {
      const int col = n0 + wn * 48 + n * 16 + lane15;
      const float Gc = G[col];
      const float Bc = Bt[col];
      #pragma unroll
      for (int r = 0; r < 4; ++r) {
        out[(size_t)(rowb + r) * 768 + col] = st[r].x * acc[m][n][r] + st[r].y * Gc + Bc;
      }
    }
  }
#undef STG1
#undef STG2
#undef RA03
#undef RA46
#undef RB
#undef M03
#undef M46
#undef BARLG
#undef BARE
#undef PR1
#undef PR0
#undef VMC
#undef PAIR
}

// ---------------------------------------------------------------------------
// Workspace layout (bytes):
//   V     : 0            57,802,752
//   w2t   : 57,802,752    3,538,944
//   stats : 61,341,696      100,352
//   G     : 61,442,048        3,072
//   Bt    : 61,445,120        3,072
//   Gp    : 61,448,192      442,368
//   Bp    : 61,890,560      442,368   -> total 62,332,928
// ---------------------------------------------------------------------------
extern "C" void kernel_launch(void* const* d_in, const int* in_sizes, int n_in,
                              void* d_out, int out_size, void* d_ws, size_t ws_size,
                              hipStream_t stream) {
  const float* x     = (const float*)d_in[0];
  const float* gamma = (const float*)d_in[1];
  const float* beta  = (const float*)d_in[2];
  const float* w     = (const float*)d_in[3];
  const float* bvec  = (const float*)d_in[4];
  float* out = (float*)d_out;

  char* ws = (char*)d_ws;
  unsigned short* V   = (unsigned short*)(ws);
  unsigned short* w2t = (unsigned short*)(ws + 57802752);
  float2* stats       = (float2*)(ws + 61341696);
  float* G            = (float*)(ws + 61442048);
  float* Bt           = (float*)(ws + 61445120);
  float* Gp           = (float*)(ws + 61448192);
  float* Bp           = (float*)(ws + 61890560);

  spt_pack<<<896, 512, 0, stream>>>(x, V, stats);
  spt_fold_w<<<dim3(144, 3), 256, 0, stream>>>(gamma, beta, w, w2t, Gp, Bp);
  spt_gb<<<3, 256, 0, stream>>>(Gp, Bp, bvec, G, Bt);
  spt_gemm<<<224, 512, 0, stream>>>(V, w2t, stats, G, Bt, out);
}

// Round 13
// 90.258 us; speedup vs baseline: 1.2970x; 1.0176x over previous
//
#include <hip/hip_runtime.h>

// ShiftedPatchTokenization on MI355X (gfx950)
// x[64,3,224,224] f32 -> out[64,196,768] f32
// spt_prep (pack || fold_w fused, one launch) -> gb -> 224x96 dbuf MFMA GEMM.

typedef short bf16x8 __attribute__((ext_vector_type(8)));
typedef unsigned short u16x8 __attribute__((ext_vector_type(8)));
typedef float f32x4 __attribute__((ext_vector_type(4)));

#define GLOBAL_AS __attribute__((address_space(1)))
#define LDS_AS __attribute__((address_space(3)))

__device__ __forceinline__ unsigned short f2bf(float f) {
  union { float f; unsigned int u; } v;
  v.f = f;
  unsigned int u = v.u;
  unsigned int r = (u + 0x7FFFu + ((u >> 16) & 1u)) >> 16;  // RNE
  return (unsigned short)r;
}

// ---------------------------------------------------------------------------
// Kernel 1: FUSED prep. Blocks [0,896): pack V[12544][2304] bf16 + LN stats.
// Blocks [896,1112): fold gamma*w -> w2t[768][2304] bf16 + G/Bt partials
// (each 512-thread block = 2 independent 256-thread halves, 32 k-rows).
// Pack and fold are independent -> fold fills CUs as pack blocks drain.
// ---------------------------------------------------------------------------
__global__ __launch_bounds__(512) void spt_prep(
    const float* __restrict__ x, const float* __restrict__ gamma,
    const float* __restrict__ beta, const float* __restrict__ w,
    unsigned short* __restrict__ V, float2* __restrict__ stats,
    unsigned short* __restrict__ w2t, float* __restrict__ Gp,
    float* __restrict__ Bp)
{
  __shared__ __align__(16) char smem[79072];  // max(pack 79072, fold 32896)
  const int t = threadIdx.x;

  if (blockIdx.x < 896) {
    // ------------------------- PACK -------------------------
    unsigned short* slab = (unsigned short*)smem;          // [14][2312]
    float* sred = (float*)(smem + 64736);                  // [8][224]
    float* qred = sred + 8 * 224;                          // [8][224]
    const int orig = blockIdx.x;
    const int bi = (orig & 7) * 112 + (orig >> 3);         // 896 = 8*112
    const int b = bi / 14, hi = bi % 14;
    const float TW = 16.0f / 224.0f;

    const int q = t % 56;
    const int grp = t / 56;     // 0..9; active grp<8
    const int x4 = q * 4;

    int sloff[4];
    {
      int wi = x4 % 14, p2 = x4 / 14;
      #pragma unroll
      for (int j = 0; j < 4; ++j) {
        sloff[j] = wi * 2312 + p2;
        if (++wi == 14) { wi = 0; ++p2; }
      }
    }

    if (grp < 8) {
      f32x4 sAcc = {0.f, 0.f, 0.f, 0.f}, qAcc = {0.f, 0.f, 0.f, 0.f};
      #pragma unroll
      for (int it = 0; it < 6; ++it) {
        const int cp = grp * 6 + it;
        const int c = cp >> 4, p1 = cp & 15;
        const int y = p1 * 14 + hi;
        const float* row = x + ((size_t)(b * 3 + c)) * 50176 + (size_t)y * 224;
        const f32x4 xv = *(const f32x4*)(row + x4);
        f32x4 ra = {0.f,0.f,0.f,0.f}, rb = {0.f,0.f,0.f,0.f};
        f32x4 la = {0.f,0.f,0.f,0.f}, lb = {0.f,0.f,0.f,0.f};
        if (q < 54) {
          ra = *(const f32x4*)(row + x4 + 8);
          if (y < 223) rb = *(const f32x4*)(row + x4 + 8 + 224);
        }
        if (q >= 2) {
          la = *(const f32x4*)(row + x4 - 8);
          if (y > 0) lb = *(const f32x4*)(row + x4 - 8 - 224);
        }
        const f32x4 rv = (1.0f - TW) * ra + TW * rb;
        const f32x4 lv = (1.0f - TW) * la + TW * lb;
        sAcc += xv + 2.0f * (lv + rv);
        qAcc += xv * xv + 2.0f * (lv * lv + rv * rv);
        const int kb = c * 256 + p1 * 16;
        #pragma unroll
        for (int j = 0; j < 4; ++j) {
          slab[sloff[j] + kb]        = f2bf(xv[j]);
          slab[sloff[j] + kb + 768]  = f2bf(lv[j]);
          slab[sloff[j] + kb + 1536] = f2bf(rv[j]);
        }
      }
      #pragma unroll
      for (int j = 0; j < 4; ++j) {
        sred[grp * 224 + x4 + j] = sAcc[j];
        qred[grp * 224 + x4 + j] = qAcc[j];
      }
    }
    __syncthreads();

    if (t < 224) {
      float ss = 0.f, qq = 0.f;
      #pragma unroll
      for (int g = 0; g < 8; ++g) { ss += sred[g * 224 + t]; qq += qred[g * 224 + t]; }
      sred[t] = ss;  // column-private
      qred[t] = qq;
    }
    __syncthreads();

    const int tok0 = b * 196 + hi * 14;
    if (t < 14) {
      float S = 0.f, Q = 0.f;
      #pragma unroll
      for (int p = 0; p < 16; ++p) { S += sred[t + 14 * p]; Q += qred[t + 14 * p]; }
      const float mu = S / 3840.f;
      const float var = Q / 3840.f - mu * mu;
      const float r = rsqrtf(var + 1e-5f);
      stats[tok0 + t] = make_float2(r, -mu * r);
    }

    for (int i = t; i < 14 * 288; i += 512) {
      const int wi2 = i / 288, off = i % 288;
      *(u16x8*)&V[(size_t)(tok0 + wi2) * 2304 + off * 8] =
          *(const u16x8*)&slab[wi2 * 2312 + off * 8];
    }
  } else {
    // ------------------------- FOLD_W -------------------------
    float* tileF = (float*)smem;                           // [32][257]
    const int bx = blockIdx.x - 896;   // 0..215
    const int fx = bx / 3;             // 0..71
    const int fy = bx % 3;
    const int half = t >> 8;           // two independent 256-thread halves
    const int tt = t & 255;
    const int j = fy * 256 + tt;
    const int f2blk = fx * 32 + half * 16;

    float gacc = 0.f, bacc = 0.f;
    #pragma unroll
    for (int i = 0; i < 16; ++i) {
      const int f2 = f2blk + i;
      const int g = f2 / 768;
      const int rem = f2 % 768;  // c*256 + p1*16 + p2
      float v, bv;
      if (g == 0) {
        const int f = rem;
        const float wv = w[(size_t)f * 768 + j];
        v = gamma[f] * wv;
        bv = beta[f] * wv;
      } else if (g == 1) {
        const int fa = 768 + rem, fb = 2304 + rem;   // left_up, left_down
        const float wa = w[(size_t)fa * 768 + j], wb = w[(size_t)fb * 768 + j];
        v = gamma[fa] * wa + gamma[fb] * wb;
        bv = beta[fa] * wa + beta[fb] * wb;
      } else {
        const int fa = 1536 + rem, fb = 3072 + rem;  // right_up, right_down
        const float wa = w[(size_t)fa * 768 + j], wb = w[(size_t)fb * 768 + j];
        v = gamma[fa] * wa + gamma[fb] * wb;
        bv = beta[fa] * wa + beta[fb] * wb;
      }
      tileF[(half * 16 + i) * 257 + tt] = v;
      gacc += v;
      bacc += bv;
    }
    __syncthreads();
    u16x8 lo, hi;
    #pragma unroll
    for (int i = 0; i < 8; ++i) {
      lo[i] = f2bf(tileF[(half * 16 + i) * 257 + tt]);
      hi[i] = f2bf(tileF[(half * 16 + 8 + i) * 257 + tt]);
    }
    unsigned short* dst = w2t + (size_t)j * 2304 + f2blk;
    *(u16x8*)dst = lo;
    *(u16x8*)(dst + 8) = hi;
    Gp[(fx * 2 + half) * 768 + j] = gacc;
    Bp[(fx * 2 + half) * 768 + j] = bacc;
  }
}

// ---------------------------------------------------------------------------
// Kernel 2: reduce 144 partials -> G[768], Bt[768] (+b). grid 3, block 256
// ---------------------------------------------------------------------------
__global__ __launch_bounds__(256) void spt_gb(
    const float* __restrict__ Gp, const float* __restrict__ Bp,
    const float* __restrict__ bvec, float* __restrict__ G, float* __restrict__ Bt)
{
  const int j = blockIdx.x * 256 + threadIdx.x;
  float g = 0.f, bb = 0.f;
  for (int i = 0; i < 144; ++i) {
    g += Gp[i * 768 + j];
    bb += Bp[i * 768 + j];
  }
  G[j] = g;
  Bt[j] = bb + bvec[j];
}

// ---------------------------------------------------------------------------
// Kernel 3: GEMM  out[m][j] = r_m * (V[m,:] . w2t[j,:]) + (-mu*r)_m * G[j] + Bt[j]
// Best measured variant (r9 minus null s_sleep): 224x96 tile, BK=64, 4 waves
// (2x2, wave 112x48), dbuf 80 KiB -> 2 blocks/CU, counted vmcnt(10), raw
// s_barrier, XOR swizzle w/ pre-swizzled source, hoisted frags + setprio.
// grid 448 = 56m x 8n, exact XCD swizzle, N-fastest.
// ---------------------------------------------------------------------------
__global__ __launch_bounds__(256, 2) void spt_gemm(
    const unsigned short* __restrict__ V, const unsigned short* __restrict__ w2t,
    const float2* __restrict__ stats, const float* __restrict__ G,
    const float* __restrict__ Bt, float* __restrict__ out)
{
  __shared__ unsigned short Alds[2][224 * 64];
  __shared__ unsigned short Blds[2][96 * 64];

  const int orig = blockIdx.x;
  const int wgid = (orig & 7) * 56 + (orig >> 3);  // exact: 448 = 8 * 56
  const int m0 = (wgid >> 3) * 224;
  const int n0 = (wgid & 7) * 96;
  const int t = threadIdx.x;
  const int w = t >> 6, l = t & 63;
  const int wr = w >> 1;   // 0..1 -> 112-row half
  const int wn = w & 1;    // 0..1 -> 48-col slice

  f32x4 acc[7][3] = {};

#define STAGE(pb, kt)                                                          \
  {                                                                            \
    const int k0s = (kt) << 6;                                                 \
    _Pragma("unroll") for (int i = 0; i < 7; ++i) {                            \
      const int c = i * 256 + t;                                               \
      const int row = c >> 3;                                                  \
      const int srcel = (((c & 7) ^ (row & 7)) << 3);                          \
      const unsigned short* ga = V + (size_t)(m0 + row) * 2304 + k0s + srcel;  \
      __builtin_amdgcn_global_load_lds((const GLOBAL_AS unsigned int*)ga,      \
          (LDS_AS unsigned int*)&Alds[pb][i * 2048 + w * 512], 16, 0, 0);      \
    }                                                                          \
    _Pragma("unroll") for (int i = 0; i < 3; ++i) {                            \
      const int c = i * 256 + t;                                               \
      const int row = c >> 3;                                                  \
      const int srcel = (((c & 7) ^ (row & 7)) << 3);                          \
      const unsigned short* gb = w2t + (size_t)(n0 + row) * 2304 + k0s + srcel;\
      __builtin_amdgcn_global_load_lds((const GLOBAL_AS unsigned int*)gb,      \
          (LDS_AS unsigned int*)&Blds[pb][i * 2048 + w * 512], 16, 0, 0);      \
    }                                                                          \
  }

#define COMPUTE(pb)                                                            \
  {                                                                            \
    const int lane15 = l & 15;                                                 \
    const int kcol = (l >> 4) << 4;                                            \
    bf16x8 bF[2][3], aF[2][7];                                                 \
    _Pragma("unroll") for (int kk = 0; kk < 2; ++kk) {                         \
      const int kb = kk * 64 + kcol;                                           \
      _Pragma("unroll") for (int n = 0; n < 3; ++n) {                          \
        const int row = wn * 48 + n * 16 + lane15;                             \
        const int phys = row * 128 + (kb ^ ((row & 7) << 4));                  \
        bF[kk][n] = *(const bf16x8*)&Blds[pb][phys >> 1];                      \
      }                                                                        \
      _Pragma("unroll") for (int m = 0; m < 7; ++m) {                          \
        const int row = wr * 112 + m * 16 + lane15;                            \
        const int phys = row * 128 + (kb ^ ((row & 7) << 4));                  \
        aF[kk][m] = *(const bf16x8*)&Alds[pb][phys >> 1];                      \
      }                                                                        \
    }                                                                          \
    __builtin_amdgcn_s_setprio(1);                                             \
    _Pragma("unroll") for (int kk = 0; kk < 2; ++kk)                           \
      _Pragma("unroll") for (int m = 0; m < 7; ++m)                            \
        _Pragma("unroll") for (int n = 0; n < 3; ++n)                          \
          acc[m][n] = __builtin_amdgcn_mfma_f32_16x16x32_bf16(aF[kk][m],       \
                          bF[kk][n], acc[m][n], 0, 0, 0);                      \
    __builtin_amdgcn_s_setprio(0);                                             \
  }

  STAGE(0, 0);
  int pb = 0;
  for (int kt = 0; kt < 35; ++kt) {
    STAGE(pb ^ 1, kt + 1);
    // wait for the 10 oldest loads (step kt); 10 newest (kt+1) stay in flight
    asm volatile("s_waitcnt vmcnt(10)\n\ts_barrier" ::: "memory");
    COMPUTE(pb);
    asm volatile("s_barrier" ::: "memory");  // reads of buf pb done before restage
    pb ^= 1;
  }
  asm volatile("s_waitcnt vmcnt(0)\n\ts_barrier" ::: "memory");
  COMPUTE(pb);

  // Epilogue: C/D frag layout col = l&15, row = (l>>4)*4 + reg
  const int lane15 = l & 15;
  const int lg = (l >> 4) * 4;
  #pragma unroll
  for (int m = 0; m < 7; ++m) {
    const int rowb = m0 + wr * 112 + m * 16 + lg;
    float2 st[4];
    #pragma unroll
    for (int r = 0; r < 4; ++r) st[r] = stats[rowb + r];
    #pragma unroll
    for (int n = 0; n < 3; ++n) {
      const int col = n0 + wn * 48 + n * 16 + lane15;
      const float Gc = G[col];
      const float Bc = Bt[col];
      #pragma unroll
      for (int r = 0; r < 4; ++r) {
        out[(size_t)(rowb + r) * 768 + col] = st[r].x * acc[m][n][r] + st[r].y * Gc + Bc;
      }
    }
  }
#undef STAGE
#undef COMPUTE
}

// ---------------------------------------------------------------------------
// Workspace layout (bytes):
//   V     : 0            57,802,752
//   w2t   : 57,802,752    3,538,944
//   stats : 61,341,696      100,352
//   G     : 61,442,048        3,072
//   Bt    : 61,445,120        3,072
//   Gp    : 61,448,192      442,368
//   Bp    : 61,890,560      442,368   -> total 62,332,928
// ---------------------------------------------------------------------------
extern "C" void kernel_launch(void* const* d_in, const int* in_sizes, int n_in,
                              void* d_out, int out_size, void* d_ws, size_t ws_size,
                              hipStream_t stream) {
  const float* x     = (const float*)d_in[0];
  const float* gamma = (const float*)d_in[1];
  const float* beta  = (const float*)d_in[2];
  const float* w     = (const float*)d_in[3];
  const float* bvec  = (const float*)d_in[4];
  float* out = (float*)d_out;

  char* ws = (char*)d_ws;
  unsigned short* V   = (unsigned short*)(ws);
  unsigned short* w2t = (unsigned short*)(ws + 57802752);
  float2* stats       = (float2*)(ws + 61341696);
  float* G            = (float*)(ws + 61442048);
  float* Bt           = (float*)(ws + 61445120);
  float* Gp           = (float*)(ws + 61448192);
  float* Bp           = (float*)(ws + 61890560);

  spt_prep<<<1112, 512, 0, stream>>>(x, gamma, beta, w, V, stats, w2t, Gp, Bp);
  spt_gb<<<3, 256, 0, stream>>>(Gp, Bp, bvec, G, Bt);
  spt_gemm<<<448, 256, 0, stream>>>(V, w2t, stats, G, Bt, out);
}

// Round 14
// 86.216 us; speedup vs baseline: 1.3578x; 1.0469x over previous
//
#include <hip/hip_runtime.h>

// ShiftedPatchTokenization on MI355X (gfx950)
// x[64,3,224,224] f32 -> out[64,196,768] f32
// spt_prep (c-split pack || fold_w, one launch) -> gb (+stats finish) ->
// 224x96 dbuf MFMA GEMM (best measured variant, unchanged).

typedef short bf16x8 __attribute__((ext_vector_type(8)));
typedef unsigned short u16x8 __attribute__((ext_vector_type(8)));
typedef float f32x4 __attribute__((ext_vector_type(4)));

#define GLOBAL_AS __attribute__((address_space(1)))
#define LDS_AS __attribute__((address_space(3)))

__device__ __forceinline__ unsigned short f2bf(float f) {
  union { float f; unsigned int u; } v;
  v.f = f;
  unsigned int u = v.u;
  unsigned int r = (u + 0x7FFFu + ((u >> 16) & 1u)) >> 16;  // RNE
  return (unsigned short)r;
}

// ---------------------------------------------------------------------------
// Kernel 1: FUSED prep, grid 2904 x 512.
// Per XCD chunk of 363: local<336 -> PACK unit (c-split: one (b,hi,c) per
// block, 2-iter latency chain, ~36 KB LDS -> 3 blocks/CU); local>=336 ->
// FOLD unit (2x256-thread halves, 32 k-rows of gamma*w fold).
// Pack writes V segments + per-(token,c) stats partials Sp/Qp.
// ---------------------------------------------------------------------------
__global__ __launch_bounds__(512, 6) void spt_prep(
    const float* __restrict__ x, const float* __restrict__ gamma,
    const float* __restrict__ beta, const float* __restrict__ w,
    unsigned short* __restrict__ V, float* __restrict__ Sp,
    float* __restrict__ Qp, unsigned short* __restrict__ w2t,
    float* __restrict__ Gp, float* __restrict__ Bp)
{
  __shared__ __align__(16) char smem[36064];  // max(pack 36064, fold 32896)
  const int t = threadIdx.x;
  const int xcd = blockIdx.x & 7;
  const int local = blockIdx.x >> 3;  // 0..362

  if (local < 336) {
    // ------------------------- PACK (one channel) -------------------------
    unsigned short* slab = (unsigned short*)smem;   // [14][776]: 3 segs of 256 + pad
    float* sred = (float*)(smem + 21728);           // [8][224]
    float* qred = sred + 1792;
    const int bi = xcd * 336 + local;               // (b*14+hi)*3 + c
    const int th = bi / 3, c = bi % 3;
    const int b = th / 14, hi = th % 14;
    const float TW = 16.0f / 224.0f;

    const int q = t % 56;
    const int grp = t / 56;     // 0..9; active grp<8
    const int x4 = q * 4;

    int sloff[4];
    {
      int wi = x4 % 14, p2 = x4 / 14;
      #pragma unroll
      for (int j = 0; j < 4; ++j) {
        sloff[j] = wi * 776 + p2;
        if (++wi == 14) { wi = 0; ++p2; }
      }
    }

    if (grp < 8) {
      f32x4 sAcc = {0.f, 0.f, 0.f, 0.f}, qAcc = {0.f, 0.f, 0.f, 0.f};
      #pragma unroll
      for (int it = 0; it < 2; ++it) {
        const int p1 = grp * 2 + it;
        const int y = p1 * 14 + hi;
        const float* row = x + ((size_t)(b * 3 + c)) * 50176 + (size_t)y * 224;
        const f32x4 xv = *(const f32x4*)(row + x4);
        f32x4 ra = {0.f,0.f,0.f,0.f}, rb = {0.f,0.f,0.f,0.f};
        f32x4 la = {0.f,0.f,0.f,0.f}, lb = {0.f,0.f,0.f,0.f};
        if (q < 54) {
          ra = *(const f32x4*)(row + x4 + 8);
          if (y < 223) rb = *(const f32x4*)(row + x4 + 8 + 224);
        }
        if (q >= 2) {
          la = *(const f32x4*)(row + x4 - 8);
          if (y > 0) lb = *(const f32x4*)(row + x4 - 8 - 224);
        }
        const f32x4 rv = (1.0f - TW) * ra + TW * rb;
        const f32x4 lv = (1.0f - TW) * la + TW * lb;
        sAcc += xv + 2.0f * (lv + rv);
        qAcc += xv * xv + 2.0f * (lv * lv + rv * rv);
        const int kb = p1 * 16;
        #pragma unroll
        for (int j = 0; j < 4; ++j) {
          slab[sloff[j] + kb]        = f2bf(xv[j]);   // seg 0: x
          slab[sloff[j] + kb + 256]  = f2bf(lv[j]);   // seg 1: left
          slab[sloff[j] + kb + 512]  = f2bf(rv[j]);   // seg 2: right
        }
      }
      #pragma unroll
      for (int j = 0; j < 4; ++j) {
        sred[grp * 224 + x4 + j] = sAcc[j];
        qred[grp * 224 + x4 + j] = qAcc[j];
      }
    }
    __syncthreads();

    if (t < 224) {
      float ss = 0.f, qq = 0.f;
      #pragma unroll
      for (int g = 0; g < 8; ++g) { ss += sred[g * 224 + t]; qq += qred[g * 224 + t]; }
      sred[t] = ss;  // column-private
      qred[t] = qq;
    }
    __syncthreads();

    const int tok0 = b * 196 + hi * 14;
    if (t < 14) {
      float S = 0.f, Q = 0.f;
      #pragma unroll
      for (int p = 0; p < 16; ++p) { S += sred[t + 14 * p]; Q += qred[t + 14 * p]; }
      Sp[c * 12544 + tok0 + t] = S;
      Qp[c * 12544 + tok0 + t] = Q;
    }

    // copy-out: 14 tokens x 3 segs x 32 16B-chunks = 1344 chunks
    for (int i = t; i < 1344; i += 512) {
      const int wi2 = i / 96, s = i % 96;
      const int g = s >> 5, i8 = s & 31;
      *(u16x8*)&V[(size_t)(tok0 + wi2) * 2304 + g * 768 + c * 256 + i8 * 8] =
          *(const u16x8*)&slab[wi2 * 776 + g * 256 + i8 * 8];
    }
  } else {
    // ------------------------- FOLD_W -------------------------
    float* tileF = (float*)smem;                    // [32][257]
    const int fu = xcd * 27 + (local - 336);        // 0..215
    const int fx = fu / 3;                          // 0..71
    const int fy = fu % 3;
    const int half = t >> 8;                        // 2 independent halves
    const int tt = t & 255;
    const int j = fy * 256 + tt;
    const int f2blk = fx * 32 + half * 16;

    float gacc = 0.f, bacc = 0.f;
    #pragma unroll
    for (int i = 0; i < 16; ++i) {
      const int f2 = f2blk + i;
      const int g = f2 / 768;
      const int rem = f2 % 768;  // c*256 + p1*16 + p2
      float v, bv;
      if (g == 0) {
        const int f = rem;
        const float wv = w[(size_t)f * 768 + j];
        v = gamma[f] * wv;
        bv = beta[f] * wv;
      } else if (g == 1) {
        const int fa = 768 + rem, fb = 2304 + rem;   // left_up, left_down
        const float wa = w[(size_t)fa * 768 + j], wb = w[(size_t)fb * 768 + j];
        v = gamma[fa] * wa + gamma[fb] * wb;
        bv = beta[fa] * wa + beta[fb] * wb;
      } else {
        const int fa = 1536 + rem, fb = 3072 + rem;  // right_up, right_down
        const float wa = w[(size_t)fa * 768 + j], wb = w[(size_t)fb * 768 + j];
        v = gamma[fa] * wa + gamma[fb] * wb;
        bv = beta[fa] * wa + beta[fb] * wb;
      }
      tileF[(half * 16 + i) * 257 + tt] = v;
      gacc += v;
      bacc += bv;
    }
    __syncthreads();
    u16x8 lo, hi;
    #pragma unroll
    for (int i = 0; i < 8; ++i) {
      lo[i] = f2bf(tileF[(half * 16 + i) * 257 + tt]);
      hi[i] = f2bf(tileF[(half * 16 + 8 + i) * 257 + tt]);
    }
    unsigned short* dst = w2t + (size_t)j * 2304 + f2blk;
    *(u16x8*)dst = lo;
    *(u16x8*)(dst + 8) = hi;
    Gp[(fx * 2 + half) * 768 + j] = gacc;
    Bp[(fx * 2 + half) * 768 + j] = bacc;
  }
}

// ---------------------------------------------------------------------------
// Kernel 2: blocks 0-2: reduce 144 partials -> G[768], Bt[768] (+b).
// blocks 3-51: finish LN stats (sum 3 channel partials, 256 tokens each).
// grid 52, block 256
// ---------------------------------------------------------------------------
__global__ __launch_bounds__(256) void spt_gb(
    const float* __restrict__ Gp, const float* __restrict__ Bp,
    const float* __restrict__ bvec, const float* __restrict__ Sp,
    const float* __restrict__ Qp, float* __restrict__ G,
    float* __restrict__ Bt, float2* __restrict__ stats)
{
  const int t = threadIdx.x;
  if (blockIdx.x < 3) {
    const int j = blockIdx.x * 256 + t;
    float g = 0.f, bb = 0.f;
    for (int i = 0; i < 144; ++i) {
      g += Gp[i * 768 + j];
      bb += Bp[i * 768 + j];
    }
    G[j] = g;
    Bt[j] = bb + bvec[j];
  } else {
    const int tok = (blockIdx.x - 3) * 256 + t;  // 49*256 = 12544
    const float S = Sp[tok] + Sp[12544 + tok] + Sp[25088 + tok];
    const float Q = Qp[tok] + Qp[12544 + tok] + Qp[25088 + tok];
    const float mu = S / 3840.f;
    const float var = Q / 3840.f - mu * mu;
    const float r = rsqrtf(var + 1e-5f);
    stats[tok] = make_float2(r, -mu * r);
  }
}

// ---------------------------------------------------------------------------
// Kernel 3: GEMM  out[m][j] = r_m * (V[m,:] . w2t[j,:]) + (-mu*r)_m * G[j] + Bt[j]
// Best measured variant: 224x96 tile, BK=64, 4 waves (2x2, wave 112x48),
// dbuf 80 KiB -> 2 blocks/CU, counted vmcnt(10), raw s_barrier, XOR swizzle
// w/ pre-swizzled source, hoisted frags + setprio.
// grid 448 = 56m x 8n, exact XCD swizzle, N-fastest.
// ---------------------------------------------------------------------------
__global__ __launch_bounds__(256, 2) void spt_gemm(
    const unsigned short* __restrict__ V, const unsigned short* __restrict__ w2t,
    const float2* __restrict__ stats, const float* __restrict__ G,
    const float* __restrict__ Bt, float* __restrict__ out)
{
  __shared__ unsigned short Alds[2][224 * 64];
  __shared__ unsigned short Blds[2][96 * 64];

  const int orig = blockIdx.x;
  const int wgid = (orig & 7) * 56 + (orig >> 3);  // exact: 448 = 8 * 56
  const int m0 = (wgid >> 3) * 224;
  const int n0 = (wgid & 7) * 96;
  const int t = threadIdx.x;
  const int w = t >> 6, l = t & 63;
  const int wr = w >> 1;   // 0..1 -> 112-row half
  const int wn = w & 1;    // 0..1 -> 48-col slice

  f32x4 acc[7][3] = {};

#define STAGE(pb, kt)                                                          \
  {                                                                            \
    const int k0s = (kt) << 6;                                                 \
    _Pragma("unroll") for (int i = 0; i < 7; ++i) {                            \
      const int c = i * 256 + t;                                               \
      const int row = c >> 3;                                                  \
      const int srcel = (((c & 7) ^ (row & 7)) << 3);                          \
      const unsigned short* ga = V + (size_t)(m0 + row) * 2304 + k0s + srcel;  \
      __builtin_amdgcn_global_load_lds((const GLOBAL_AS unsigned int*)ga,      \
          (LDS_AS unsigned int*)&Alds[pb][i * 2048 + w * 512], 16, 0, 0);      \
    }                                                                          \
    _Pragma("unroll") for (int i = 0; i < 3; ++i) {                            \
      const int c = i * 256 + t;                                               \
      const int row = c >> 3;                                                  \
      const int srcel = (((c & 7) ^ (row & 7)) << 3);                          \
      const unsigned short* gb = w2t + (size_t)(n0 + row) * 2304 + k0s + srcel;\
      __builtin_amdgcn_global_load_lds((const GLOBAL_AS unsigned int*)gb,      \
          (LDS_AS unsigned int*)&Blds[pb][i * 2048 + w * 512], 16, 0, 0);      \
    }                                                                          \
  }

#define COMPUTE(pb)                                                            \
  {                                                                            \
    const int lane15 = l & 15;                                                 \
    const int kcol = (l >> 4) << 4;                                            \
    bf16x8 bF[2][3], aF[2][7];                                                 \
    _Pragma("unroll") for (int kk = 0; kk < 2; ++kk) {                         \
      const int kb = kk * 64 + kcol;                                           \
      _Pragma("unroll") for (int n = 0; n < 3; ++n) {                          \
        const int row = wn * 48 + n * 16 + lane15;                             \
        const int phys = row * 128 + (kb ^ ((row & 7) << 4));                  \
        bF[kk][n] = *(const bf16x8*)&Blds[pb][phys >> 1];                      \
      }                                                                        \
      _Pragma("unroll") for (int m = 0; m < 7; ++m) {                          \
        const int row = wr * 112 + m * 16 + lane15;                            \
        const int phys = row * 128 + (kb ^ ((row & 7) << 4));                  \
        aF[kk][m] = *(const bf16x8*)&Alds[pb][phys >> 1];                      \
      }                                                                        \
    }                                                                          \
    __builtin_amdgcn_s_setprio(1);                                             \
    _Pragma("unroll") for (int kk = 0; kk < 2; ++kk)                           \
      _Pragma("unroll") for (int m = 0; m < 7; ++m)                            \
        _Pragma("unroll") for (int n = 0; n < 3; ++n)                          \
          acc[m][n] = __builtin_amdgcn_mfma_f32_16x16x32_bf16(aF[kk][m],       \
                          bF[kk][n], acc[m][n], 0, 0, 0);                      \
    __builtin_amdgcn_s_setprio(0);                                             \
  }

  STAGE(0, 0);
  int pb = 0;
  for (int kt = 0; kt < 35; ++kt) {
    STAGE(pb ^ 1, kt + 1);
    // wait for the 10 oldest loads (step kt); 10 newest (kt+1) stay in flight
    asm volatile("s_waitcnt vmcnt(10)\n\ts_barrier" ::: "memory");
    COMPUTE(pb);
    asm volatile("s_barrier" ::: "memory");  // reads of buf pb done before restage
    pb ^= 1;
  }
  asm volatile("s_waitcnt vmcnt(0)\n\ts_barrier" ::: "memory");
  COMPUTE(pb);

  // Epilogue: C/D frag layout col = l&15, row = (l>>4)*4 + reg
  const int lane15 = l & 15;
  const int lg = (l >> 4) * 4;
  #pragma unroll
  for (int m = 0; m < 7; ++m) {
    const int rowb = m0 + wr * 112 + m * 16 + lg;
    float2 st[4];
    #pragma unroll
    for (int r = 0; r < 4; ++r) st[r] = stats[rowb + r];
    #pragma unroll
    for (int n = 0; n < 3; ++n) {
      const int col = n0 + wn * 48 + n * 16 + lane15;
      const float Gc = G[col];
      const float Bc = Bt[col];
      #pragma unroll
      for (int r = 0; r < 4; ++r) {
        out[(size_t)(rowb + r) * 768 + col] = st[r].x * acc[m][n][r] + st[r].y * Gc + Bc;
      }
    }
  }
#undef STAGE
#undef COMPUTE
}

// ---------------------------------------------------------------------------
// Workspace layout (bytes):
//   V     : 0            57,802,752
//   w2t   : 57,802,752    3,538,944
//   stats : 61,341,696      100,352
//   G     : 61,442,048        3,072
//   Bt    : 61,445,120        3,072
//   Gp    : 61,448,192      442,368
//   Bp    : 61,890,560      442,368
//   Sp    : 62,332,928      150,528
//   Qp    : 62,483,456      150,528   -> total 62,633,984
// ---------------------------------------------------------------------------
extern "C" void kernel_launch(void* const* d_in, const int* in_sizes, int n_in,
                              void* d_out, int out_size, void* d_ws, size_t ws_size,
                              hipStream_t stream) {
  const float* x     = (const float*)d_in[0];
  const float* gamma = (const float*)d_in[1];
  const float* beta  = (const float*)d_in[2];
  const float* w     = (const float*)d_in[3];
  const float* bvec  = (const float*)d_in[4];
  float* out = (float*)d_out;

  char* ws = (char*)d_ws;
  unsigned short* V   = (unsigned short*)(ws);
  unsigned short* w2t = (unsigned short*)(ws + 57802752);
  float2* stats       = (float2*)(ws + 61341696);
  float* G            = (float*)(ws + 61442048);
  float* Bt           = (float*)(ws + 61445120);
  float* Gp           = (float*)(ws + 61448192);
  float* Bp           = (float*)(ws + 61890560);
  float* Sp           = (float*)(ws + 62332928);
  float* Qp           = (float*)(ws + 62483456);

  spt_prep<<<2904, 512, 0, stream>>>(x, gamma, beta, w, V, Sp, Qp, w2t, Gp, Bp);
  spt_gb<<<52, 256, 0, stream>>>(Gp, Bp, bvec, Sp, Qp, G, Bt, stats);
  spt_gemm<<<448, 256, 0, stream>>>(V, w2t, stats, G, Bt, out);
}